// Round 9
// baseline (300.398 us; speedup 1.0000x reference)
//
#include <hip/hip_runtime.h>
#include <math.h>

// Problem constants (match reference)
#define B 32
#define C 4
#define P (360*640)        // 230400 pixels per batch
#define L 5                // MAX_LANES
#define DELTA_V 1.0f
#define DELTA_D 6.0f

#define BLKX 45            // chunks per batch; 225 wave-steps / 45 = 5 iters exactly
#define NBLK3 (B*BLKX)     // 1440 pull partials
#define PSTRIDE 48         // padded chunk-stride of value-major partials

__device__ __forceinline__ float waveReduce(float v) {
#pragma unroll
    for (int off = 32; off; off >>= 1) v += __shfl_down(v, off, 64);
    return v;
}

// ---------------------------------------------------------------------------
// Kernel 1: segment sums, 2-channel split. Block = (chunk x, cp, batch b),
// channels 2*cp, 2*cp+1. 3 streams; iterations PAIRED with all loads hoisted
// (flat SSA, no rotation -- R5/R7 rotation pipelines spilled; R8's paired K2
// did not) -> 6 x 16B loads in flight, ~15 accumulators, fits 64 VGPRs.
// t is read 2x total (59 MB) instead of 4x (118 MB).
// cp==0 blocks also emit packed uint8 labels for kernel 2 and zero the
// finale counter. Partials value-major: partial[(b*25+v)*48+x].
// ---------------------------------------------------------------------------
__global__ __launch_bounds__(256, 4) void seg_sums_k(const int* __restrict__ tgt,
                                                     const float* __restrict__ emb,
                                                     float* __restrict__ partial,
                                                     unsigned char* __restrict__ tpk,
                                                     unsigned int* __restrict__ counter) {
    const int x = blockIdx.x, cp = blockIdx.y, b = blockIdx.z;
    const int tid = threadIdx.x;
    if (x == 0 && cp == 0 && b == 0 && tid == 0) *counter = 0u;  // visible to K2 via kernel boundary

    const int c0 = 2 * cp;
    const int4*   t4 = (const int4*)(tgt + (size_t)b * P);
    const float4* ea = (const float4*)(emb + ((size_t)b * C + c0    ) * P);
    const float4* eb = (const float4*)(emb + ((size_t)b * C + c0 + 1) * P);
    uchar4*      tp4 = (uchar4*)(tpk + (size_t)b * P);

    float s0[L], s1[L], n[L];
#pragma unroll
    for (int l = 0; l < L; ++l) { s0[l] = 0.f; s1[l] = 0.f; n[l] = 0.f; }

    auto acc1 = [&](int tt, float xa, float xb) {
#pragma unroll
        for (int l = 0; l < L; ++l) {
            float m = (tt == l + 1) ? 1.0f : 0.0f;
            n[l]  += m;
            s0[l]  = fmaf(m, xa, s0[l]);
            s1[l]  = fmaf(m, xb, s1[l]);
        }
    };
    auto consume = [&](const int4& t, const float4& va, const float4& vb) {
        acc1(t.x, va.x, vb.x);
        acc1(t.y, va.y, vb.y);
        acc1(t.z, va.z, vb.z);
        acc1(t.w, va.w, vb.w);
    };

    {   // pair (0,1)
        const int g0 = x * 256 + tid, g1 = (x + BLKX) * 256 + tid;
        int4   t0 = t4[g0], t1 = t4[g1];
        float4 a0 = ea[g0], b0 = eb[g0], a1 = ea[g1], b1 = eb[g1];
        if (cp == 0) {
            tp4[g0] = make_uchar4((unsigned char)t0.x, (unsigned char)t0.y,
                                  (unsigned char)t0.z, (unsigned char)t0.w);
            tp4[g1] = make_uchar4((unsigned char)t1.x, (unsigned char)t1.y,
                                  (unsigned char)t1.z, (unsigned char)t1.w);
        }
        consume(t0, a0, b0);
        consume(t1, a1, b1);
    }
    {   // pair (2,3)
        const int g0 = (x + 2*BLKX) * 256 + tid, g1 = (x + 3*BLKX) * 256 + tid;
        int4   t0 = t4[g0], t1 = t4[g1];
        float4 a0 = ea[g0], b0 = eb[g0], a1 = ea[g1], b1 = eb[g1];
        if (cp == 0) {
            tp4[g0] = make_uchar4((unsigned char)t0.x, (unsigned char)t0.y,
                                  (unsigned char)t0.z, (unsigned char)t0.w);
            tp4[g1] = make_uchar4((unsigned char)t1.x, (unsigned char)t1.y,
                                  (unsigned char)t1.z, (unsigned char)t1.w);
        }
        consume(t0, a0, b0);
        consume(t1, a1, b1);
    }
    {   // iteration 4
        const int g0 = (x + 4*BLKX) * 256 + tid;
        int4   t0 = t4[g0];
        float4 a0 = ea[g0], b0 = eb[g0];
        if (cp == 0)
            tp4[g0] = make_uchar4((unsigned char)t0.x, (unsigned char)t0.y,
                                  (unsigned char)t0.z, (unsigned char)t0.w);
        consume(t0, a0, b0);
    }

    // block-reduce 15 values (10 sums + 5 counts; counts written only by cp==0)
    float vals[15];
#pragma unroll
    for (int l = 0; l < L; ++l) { vals[l] = s0[l]; vals[L + l] = s1[l]; vals[10 + l] = n[l]; }

    __shared__ float red[4][15];
    const int lane = tid & 63, wave = tid >> 6;
#pragma unroll
    for (int k = 0; k < 15; ++k) {
        float r = waveReduce(vals[k]);
        if (lane == 0) red[wave][k] = r;
    }
    __syncthreads();
    if (tid < 15) {
        const float r = red[0][tid] + red[1][tid] + red[2][tid] + red[3][tid];
        int v;
        if (cp == 0) v = (tid < 10) ? tid : (10 + tid);       // c0,c1 sums; counts -> 20..24
        else         v = (tid < 10) ? (10 + tid) : -1;        // c2,c3 sums; drop dup counts
        if (v >= 0)
            partial[((size_t)b * 25 + v) * PSTRIDE + x] = r;
    }
}

// ---------------------------------------------------------------------------
// Kernel 2: pull loss + merged finale. Prologue wave-reduces this batch's
// value-major partials into means/valid (x==0 publishes for the finale).
// Main loop: packed labels (uchar4) + 4 planes, paired iterations (R8 shape).
// Finale: last block (release-acquire via __threadfence + atomicAdd) computes
// push loss + pull normalization and writes out[0].
// ---------------------------------------------------------------------------
__global__ __launch_bounds__(256, 4) void pull_k(const unsigned char* __restrict__ tpk,
                                                 const float* __restrict__ emb,
                                                 const float* __restrict__ partial,
                                                 float* __restrict__ meansG,
                                                 float* __restrict__ validG,
                                                 float* __restrict__ cntvG,
                                                 float* __restrict__ pullp,
                                                 unsigned int* __restrict__ counter,
                                                 float* __restrict__ out) {
    __shared__ float  praw[25];
    __shared__ float4 lmean[L + 1];   // label 0 -> zero mean
    __shared__ float  lvalid[L + 1];  // label 0 -> invalid
    __shared__ float  lred[4];
    __shared__ int    sLast;
    const int xb = blockIdx.x, b = blockIdx.y;
    const int tid = threadIdx.x;
    const int lane = tid & 63, wave = tid >> 6;

    // ---- prologue: reduce partials (value-major) for batch b ----
    for (int v = wave; v < 25; v += 4) {
        float pv = (lane < BLKX) ? partial[((size_t)b * 25 + v) * PSTRIDE + lane] : 0.f;
        pv = waveReduce(pv);
        if (lane == 0) praw[v] = pv;
    }
    __syncthreads();
    if (tid < L) {
        const float cnt = praw[20 + tid];
        const bool  vld = cnt > 1.5f;          // integer count > 1
        const float inv = 1.0f / fmaxf(cnt, 1.0f);
        float4 m = make_float4(praw[tid] * inv, praw[5 + tid] * inv,
                               praw[10 + tid] * inv, praw[15 + tid] * inv);
        lmean[tid + 1]  = m;
        lvalid[tid + 1] = vld ? 1.f : 0.f;
        if (xb == 0) {                          // publish for the finale
            *(float4*)(meansG + ((size_t)b * L + tid) * 4) = m;
            validG[b * L + tid] = vld ? 1.f : 0.f;
            cntvG[b * L + tid]  = vld ? cnt : 0.f;
        }
    }
    if (tid == 8) { lmean[0] = make_float4(0.f, 0.f, 0.f, 0.f); lvalid[0] = 0.f; }
    __syncthreads();

    // ---- main: packed labels + 4 planes, paired iterations (no rotation) ----
    const uchar4* tp4 = (const uchar4*)(tpk + (size_t)b * P);
    const float4* e0  = (const float4*)(emb + ((size_t)b * C + 0) * P);
    const float4* e1  = (const float4*)(emb + ((size_t)b * C + 1) * P);
    const float4* e2  = (const float4*)(emb + ((size_t)b * C + 2) * P);
    const float4* e3  = (const float4*)(emb + ((size_t)b * C + 3) * P);

    float acc = 0.f;
    auto proc1 = [&](int tt, float v0, float v1, float v2, float v3) {
        float4 m = lmean[tt];
        float d0 = v0 - m.x, d1 = v1 - m.y, d2 = v2 - m.z, d3 = v3 - m.w;
        float sq   = d0*d0 + d1*d1 + d2*d2 + d3*d3;
        float dist = sqrtf(fmaxf(sq, 1e-12f));
        float h    = fmaxf(dist - DELTA_V, 0.f);
        acc = fmaf(lvalid[tt] * h, h, acc);
    };
    auto consume = [&](uchar4 t, const float4& a0, const float4& a1,
                       const float4& a2, const float4& a3) {
        proc1(t.x, a0.x, a1.x, a2.x, a3.x);
        proc1(t.y, a0.y, a1.y, a2.y, a3.y);
        proc1(t.z, a0.z, a1.z, a2.z, a3.z);
        proc1(t.w, a0.w, a1.w, a2.w, a3.w);
    };

    {   // pair (0,1)
        const int g0 = xb * 256 + tid, g1 = (xb + BLKX) * 256 + tid;
        uchar4 t0 = tp4[g0], t1 = tp4[g1];
        float4 a0 = e0[g0], a1 = e1[g0], a2 = e2[g0], a3 = e3[g0];
        float4 b0 = e0[g1], b1 = e1[g1], b2 = e2[g1], b3 = e3[g1];
        consume(t0, a0, a1, a2, a3);
        consume(t1, b0, b1, b2, b3);
    }
    {   // pair (2,3)
        const int g0 = (xb + 2*BLKX) * 256 + tid, g1 = (xb + 3*BLKX) * 256 + tid;
        uchar4 t0 = tp4[g0], t1 = tp4[g1];
        float4 a0 = e0[g0], a1 = e1[g0], a2 = e2[g0], a3 = e3[g0];
        float4 b0 = e0[g1], b1 = e1[g1], b2 = e2[g1], b3 = e3[g1];
        consume(t0, a0, a1, a2, a3);
        consume(t1, b0, b1, b2, b3);
    }
    {   // iteration 4
        const int g0 = (xb + 4*BLKX) * 256 + tid;
        uchar4 t0 = tp4[g0];
        float4 a0 = e0[g0], a1 = e1[g0], a2 = e2[g0], a3 = e3[g0];
        consume(t0, a0, a1, a2, a3);
    }

    float r = waveReduce(acc);
    if (lane == 0) lred[wave] = r;
    __syncthreads();
    if (tid == 0) {
        pullp[b * BLKX + xb] = lred[0] + lred[1] + lred[2] + lred[3];
        __threadfence();                               // release our writes
        unsigned int old = atomicAdd(counter, 1u);     // device-scope
        sLast = (old == (unsigned int)(NBLK3 - 1)) ? 1 : 0;
    }
    __syncthreads();
    if (!sLast) return;

    // ================= finale (last block only) =================
    __threadfence();                                   // acquire others' writes
    __shared__ float red2[4][4];

    float vb = 0.f, has = 0.f;
    if (tid < B) {
        const float* mb = meansG + tid * L * 4;
        const float* vv = validG + tid * L;
        float ssum = 0.f, np = 0.f;
#pragma unroll
        for (int i = 0; i < L; ++i)
#pragma unroll
            for (int j = i + 1; j < L; ++j) {
                float ok = vv[i] * vv[j];
                float d0 = mb[i*4+0] - mb[j*4+0];
                float d1 = mb[i*4+1] - mb[j*4+1];
                float d2 = mb[i*4+2] - mb[j*4+2];
                float d3 = mb[i*4+3] - mb[j*4+3];
                float psq = d0*d0 + d1*d1 + d2*d2 + d3*d3;
                float pd  = sqrtf(fmaxf(psq, 1e-12f));
                float ph  = fmaxf(DELTA_D - pd, 0.f);
                ssum += ok * ph * ph;
                np   += ok;
            }
        if (np > 0.f) { vb = ssum / np; has = 1.f; }
    }
    float pc = (tid < B*L) ? cntvG[tid] : 0.f;
    float ps = 0.f;
    for (int i = tid; i < NBLK3; i += 256) ps += pullp[i];

    float rvb = waveReduce(vb);
    float rhs = waveReduce(has);
    float rpc = waveReduce(pc);
    float rps = waveReduce(ps);
    if (lane == 0) { red2[wave][0]=rvb; red2[wave][1]=rhs; red2[wave][2]=rpc; red2[wave][3]=rps; }
    __syncthreads();
    if (tid == 0) {
        float svb = red2[0][0]+red2[1][0]+red2[2][0]+red2[3][0];
        float shs = red2[0][1]+red2[1][1]+red2[2][1]+red2[3][1];
        float spc = red2[0][2]+red2[1][2]+red2[2][2]+red2[3][2];
        float sps = red2[0][3]+red2[1][3]+red2[2][3]+red2[3][3];
        float var = (shs > 0.f) ? svb / shs : 0.f;              // push loss
        float dl  = (spc > 0.f) ? sps / fmaxf(spc, 1.f) : 0.f;  // pull loss
        out[0] = dl + var;
    }
}

// ---------------------------------------------------------------------------
extern "C" void kernel_launch(void* const* d_in, const int* in_sizes, int n_in,
                              void* d_out, int out_size, void* d_ws, size_t ws_size,
                              hipStream_t stream) {
    const int*   tgt = (const int*)d_in[0];    // targets int32 [B,H,W]
    const float* emb = (const float*)d_in[1];  // embedding fp32 [B,C,H,W]

    // workspace: packed labels first (B*P bytes; 7372800 % 16 == 0), then floats
    unsigned char* tpk = (unsigned char*)d_ws;
    float* fbase   = (float*)((char*)d_ws + (size_t)B * P);
    float* partial = fbase;                              // B*25*48 = 38400 floats
    float* meansG  = partial + (size_t)B * 25 * PSTRIDE; // 640 (16B-aligned)
    float* validG  = meansG + (size_t)B * L * 4;         // 160
    float* cntvG   = validG + B * L;                     // 160
    float* pullp   = cntvG + B * L;                      // 1440
    unsigned int* counter = (unsigned int*)(pullp + NBLK3);
    // total ws use: ~7.6 MB

    seg_sums_k<<<dim3(BLKX, 2, B), 256, 0, stream>>>(tgt, emb, partial, tpk, counter); // 2880 blocks
    pull_k<<<dim3(BLKX, B), 256, 0, stream>>>(tpk, emb, partial, meansG, validG,
                                              cntvG, pullp, counter, (float*)d_out);   // 1440 blocks
}

// Round 10
// 260.648 us; speedup vs baseline: 1.1525x; 1.1525x over previous
//
#include <hip/hip_runtime.h>
#include <math.h>

// Problem constants (match reference)
#define B 32
#define C 4
#define P (360*640)        // 230400 pixels per batch
#define L 5                // MAX_LANES
#define DELTA_V 1.0f
#define DELTA_D 6.0f

#define BLKX 45            // chunks per batch; 225 wave-steps / 45 = 5 iters exactly
#define ITER1 5
#define NBLK3 (B*BLKX)     // 1440 pull partials
#define PSTRIDE 48         // padded chunk-stride of value-major partials

__device__ __forceinline__ float waveReduce(float v) {
#pragma unroll
    for (int off = 32; off; off >>= 1) v += __shfl_down(v, off, 64);
    return v;
}

// ---------------------------------------------------------------------------
// Kernel 0: pack labels int32 -> uint8 (read t once), compute per-(b,l)
// counts, zero the finale counter. ~30 VGPR.
// Counts value-major: partial[(b*25+(20+l))*48+x].
// ---------------------------------------------------------------------------
__global__ __launch_bounds__(256) void pack_k(const int* __restrict__ tgt,
                                              unsigned char* __restrict__ tpk,
                                              float* __restrict__ partial,
                                              unsigned int* __restrict__ counter) {
    const int x = blockIdx.x, b = blockIdx.y;
    const int tid = threadIdx.x;
    if (x == 0 && b == 0 && tid == 0) *counter = 0u;   // visible to pull_k via kernel boundary

    const int4* t4  = (const int4*)(tgt + (size_t)b * P);
    uchar4*     tp4 = (uchar4*)(tpk + (size_t)b * P);

    int4 tv[ITER1];
#pragma unroll
    for (int it = 0; it < ITER1; ++it)
        tv[it] = t4[(x + it * BLKX) * 256 + tid];

#pragma unroll
    for (int it = 0; it < ITER1; ++it)
        tp4[(x + it * BLKX) * 256 + tid] =
            make_uchar4((unsigned char)tv[it].x, (unsigned char)tv[it].y,
                        (unsigned char)tv[it].z, (unsigned char)tv[it].w);

    float n[L];
#pragma unroll
    for (int l = 0; l < L; ++l) n[l] = 0.f;
#pragma unroll
    for (int it = 0; it < ITER1; ++it) {
#pragma unroll
        for (int l = 0; l < L; ++l) {
            n[l] += (tv[it].x == l + 1) ? 1.f : 0.f;
            n[l] += (tv[it].y == l + 1) ? 1.f : 0.f;
            n[l] += (tv[it].z == l + 1) ? 1.f : 0.f;
            n[l] += (tv[it].w == l + 1) ? 1.f : 0.f;
        }
    }

    __shared__ float red[4][L];
    const int lane = tid & 63, wave = tid >> 6;
#pragma unroll
    for (int k = 0; k < L; ++k) {
        float r = waveReduce(n[k]);
        if (lane == 0) red[wave][k] = r;
    }
    __syncthreads();
    if (tid < L) {
        const float r = red[0][tid] + red[1][tid] + red[2][tid] + red[3][tid];
        partial[((size_t)b * 25 + 20 + tid) * PSTRIDE + x] = r;
    }
}

// ---------------------------------------------------------------------------
// Kernel 1: segment sums, 4-way channel split reading PACKED labels.
// Block = (chunk x, channel c, batch b). Per block: uchar4 tv[5] (5 VGPR) +
// float4 ev[5] (20) + 5 accumulators -> ~40 live, inside the 64-VGPR
// envelope (R6-proven idiom: flat register arrays, full unroll, no rotation;
// R5/R7/R9 variants with 3 streams or 15 accums all spilled to scratch).
// Sums value-major: partial[(b*25+c*5+l)*48+x].
// ---------------------------------------------------------------------------
__global__ __launch_bounds__(256, 4) void seg_sums_k(const unsigned char* __restrict__ tpk,
                                                     const float* __restrict__ emb,
                                                     float* __restrict__ partial) {
    const int x = blockIdx.x, c = blockIdx.y, b = blockIdx.z;
    const int tid = threadIdx.x;

    const uchar4* tp4 = (const uchar4*)(tpk + (size_t)b * P);
    const float4* ec  = (const float4*)(emb + ((size_t)b * C + c) * P);

    uchar4 tv[ITER1];
    float4 ev[ITER1];
#pragma unroll
    for (int it = 0; it < ITER1; ++it) {
        const int g = (x + it * BLKX) * 256 + tid;
        tv[it] = tp4[g];
        ev[it] = ec[g];
    }

    float s[L];
#pragma unroll
    for (int l = 0; l < L; ++l) s[l] = 0.f;

    auto acc1 = [&](int tt, float e) {
#pragma unroll
        for (int l = 0; l < L; ++l) {
            float m = (tt == l + 1) ? 1.0f : 0.0f;
            s[l] = fmaf(m, e, s[l]);
        }
    };
#pragma unroll
    for (int it = 0; it < ITER1; ++it) {
        acc1(tv[it].x, ev[it].x);
        acc1(tv[it].y, ev[it].y);
        acc1(tv[it].z, ev[it].z);
        acc1(tv[it].w, ev[it].w);
    }

    __shared__ float red[4][L];
    const int lane = tid & 63, wave = tid >> 6;
#pragma unroll
    for (int k = 0; k < L; ++k) {
        float r = waveReduce(s[k]);
        if (lane == 0) red[wave][k] = r;
    }
    __syncthreads();
    if (tid < L) {
        const float r = red[0][tid] + red[1][tid] + red[2][tid] + red[3][tid];
        partial[((size_t)b * 25 + c * L + tid) * PSTRIDE + x] = r;
    }
}

// ---------------------------------------------------------------------------
// Kernel 2: pull loss + merged finale (R9's working K2, verbatim structure).
// Prologue wave-reduces this batch's value-major partials into means/valid
// (x==0 publishes for the finale). Main loop: packed labels + 4 planes,
// paired iterations, flat SSA. Finale: last block via
// __threadfence + device-scope atomicAdd computes push loss and out[0].
// ---------------------------------------------------------------------------
__global__ __launch_bounds__(256, 4) void pull_k(const unsigned char* __restrict__ tpk,
                                                 const float* __restrict__ emb,
                                                 const float* __restrict__ partial,
                                                 float* __restrict__ meansG,
                                                 float* __restrict__ validG,
                                                 float* __restrict__ cntvG,
                                                 float* __restrict__ pullp,
                                                 unsigned int* __restrict__ counter,
                                                 float* __restrict__ out) {
    __shared__ float  praw[25];
    __shared__ float4 lmean[L + 1];   // label 0 -> zero mean
    __shared__ float  lvalid[L + 1];  // label 0 -> invalid
    __shared__ float  lred[4];
    __shared__ int    sLast;
    const int xb = blockIdx.x, b = blockIdx.y;
    const int tid = threadIdx.x;
    const int lane = tid & 63, wave = tid >> 6;

    // ---- prologue: reduce partials (value-major) for batch b ----
    for (int v = wave; v < 25; v += 4) {
        float pv = (lane < BLKX) ? partial[((size_t)b * 25 + v) * PSTRIDE + lane] : 0.f;
        pv = waveReduce(pv);
        if (lane == 0) praw[v] = pv;
    }
    __syncthreads();
    if (tid < L) {
        const float cnt = praw[20 + tid];
        const bool  vld = cnt > 1.5f;          // integer count > 1
        const float inv = 1.0f / fmaxf(cnt, 1.0f);
        float4 m = make_float4(praw[tid] * inv, praw[5 + tid] * inv,
                               praw[10 + tid] * inv, praw[15 + tid] * inv);
        lmean[tid + 1]  = m;
        lvalid[tid + 1] = vld ? 1.f : 0.f;
        if (xb == 0) {                          // publish for the finale
            *(float4*)(meansG + ((size_t)b * L + tid) * 4) = m;
            validG[b * L + tid] = vld ? 1.f : 0.f;
            cntvG[b * L + tid]  = vld ? cnt : 0.f;
        }
    }
    if (tid == 8) { lmean[0] = make_float4(0.f, 0.f, 0.f, 0.f); lvalid[0] = 0.f; }
    __syncthreads();

    // ---- main: packed labels + 4 planes, paired iterations (no rotation) ----
    const uchar4* tp4 = (const uchar4*)(tpk + (size_t)b * P);
    const float4* e0  = (const float4*)(emb + ((size_t)b * C + 0) * P);
    const float4* e1  = (const float4*)(emb + ((size_t)b * C + 1) * P);
    const float4* e2  = (const float4*)(emb + ((size_t)b * C + 2) * P);
    const float4* e3  = (const float4*)(emb + ((size_t)b * C + 3) * P);

    float acc = 0.f;
    auto proc1 = [&](int tt, float v0, float v1, float v2, float v3) {
        float4 m = lmean[tt];
        float d0 = v0 - m.x, d1 = v1 - m.y, d2 = v2 - m.z, d3 = v3 - m.w;
        float sq   = d0*d0 + d1*d1 + d2*d2 + d3*d3;
        float dist = sqrtf(fmaxf(sq, 1e-12f));
        float h    = fmaxf(dist - DELTA_V, 0.f);
        acc = fmaf(lvalid[tt] * h, h, acc);
    };
    auto consume = [&](uchar4 t, const float4& a0, const float4& a1,
                       const float4& a2, const float4& a3) {
        proc1(t.x, a0.x, a1.x, a2.x, a3.x);
        proc1(t.y, a0.y, a1.y, a2.y, a3.y);
        proc1(t.z, a0.z, a1.z, a2.z, a3.z);
        proc1(t.w, a0.w, a1.w, a2.w, a3.w);
    };

    {   // pair (0,1)
        const int g0 = xb * 256 + tid, g1 = (xb + BLKX) * 256 + tid;
        uchar4 t0 = tp4[g0], t1 = tp4[g1];
        float4 a0 = e0[g0], a1 = e1[g0], a2 = e2[g0], a3 = e3[g0];
        float4 b0 = e0[g1], b1 = e1[g1], b2 = e2[g1], b3 = e3[g1];
        consume(t0, a0, a1, a2, a3);
        consume(t1, b0, b1, b2, b3);
    }
    {   // pair (2,3)
        const int g0 = (xb + 2*BLKX) * 256 + tid, g1 = (xb + 3*BLKX) * 256 + tid;
        uchar4 t0 = tp4[g0], t1 = tp4[g1];
        float4 a0 = e0[g0], a1 = e1[g0], a2 = e2[g0], a3 = e3[g0];
        float4 b0 = e0[g1], b1 = e1[g1], b2 = e2[g1], b3 = e3[g1];
        consume(t0, a0, a1, a2, a3);
        consume(t1, b0, b1, b2, b3);
    }
    {   // iteration 4
        const int g0 = (xb + 4*BLKX) * 256 + tid;
        uchar4 t0 = tp4[g0];
        float4 a0 = e0[g0], a1 = e1[g0], a2 = e2[g0], a3 = e3[g0];
        consume(t0, a0, a1, a2, a3);
    }

    float r = waveReduce(acc);
    if (lane == 0) lred[wave] = r;
    __syncthreads();
    if (tid == 0) {
        pullp[b * BLKX + xb] = lred[0] + lred[1] + lred[2] + lred[3];
        __threadfence();                               // release our writes
        unsigned int old = atomicAdd(counter, 1u);     // device-scope
        sLast = (old == (unsigned int)(NBLK3 - 1)) ? 1 : 0;
    }
    __syncthreads();
    if (!sLast) return;

    // ================= finale (last block only) =================
    __threadfence();                                   // acquire others' writes
    __shared__ float red2[4][4];

    float vb = 0.f, has = 0.f;
    if (tid < B) {
        const float* mb = meansG + tid * L * 4;
        const float* vv = validG + tid * L;
        float ssum = 0.f, np = 0.f;
#pragma unroll
        for (int i = 0; i < L; ++i)
#pragma unroll
            for (int j = i + 1; j < L; ++j) {
                float ok = vv[i] * vv[j];
                float d0 = mb[i*4+0] - mb[j*4+0];
                float d1 = mb[i*4+1] - mb[j*4+1];
                float d2 = mb[i*4+2] - mb[j*4+2];
                float d3 = mb[i*4+3] - mb[j*4+3];
                float psq = d0*d0 + d1*d1 + d2*d2 + d3*d3;
                float pd  = sqrtf(fmaxf(psq, 1e-12f));
                float ph  = fmaxf(DELTA_D - pd, 0.f);
                ssum += ok * ph * ph;
                np   += ok;
            }
        if (np > 0.f) { vb = ssum / np; has = 1.f; }
    }
    float pc = (tid < B*L) ? cntvG[tid] : 0.f;
    float ps = 0.f;
    for (int i = tid; i < NBLK3; i += 256) ps += pullp[i];

    float rvb = waveReduce(vb);
    float rhs = waveReduce(has);
    float rpc = waveReduce(pc);
    float rps = waveReduce(ps);
    if (lane == 0) { red2[wave][0]=rvb; red2[wave][1]=rhs; red2[wave][2]=rpc; red2[wave][3]=rps; }
    __syncthreads();
    if (tid == 0) {
        float svb = red2[0][0]+red2[1][0]+red2[2][0]+red2[3][0];
        float shs = red2[0][1]+red2[1][1]+red2[2][1]+red2[3][1];
        float spc = red2[0][2]+red2[1][2]+red2[2][2]+red2[3][2];
        float sps = red2[0][3]+red2[1][3]+red2[2][3]+red2[3][3];
        float var = (shs > 0.f) ? svb / shs : 0.f;              // push loss
        float dl  = (spc > 0.f) ? sps / fmaxf(spc, 1.f) : 0.f;  // pull loss
        out[0] = dl + var;
    }
}

// ---------------------------------------------------------------------------
extern "C" void kernel_launch(void* const* d_in, const int* in_sizes, int n_in,
                              void* d_out, int out_size, void* d_ws, size_t ws_size,
                              hipStream_t stream) {
    const int*   tgt = (const int*)d_in[0];    // targets int32 [B,H,W]
    const float* emb = (const float*)d_in[1];  // embedding fp32 [B,C,H,W]

    // workspace: packed labels first (B*P bytes; 7372800 % 16 == 0), then floats
    unsigned char* tpk = (unsigned char*)d_ws;
    float* fbase   = (float*)((char*)d_ws + (size_t)B * P);
    float* partial = fbase;                              // B*25*48 = 38400 floats
    float* meansG  = partial + (size_t)B * 25 * PSTRIDE; // 640 (16B-aligned)
    float* validG  = meansG + (size_t)B * L * 4;         // 160
    float* cntvG   = validG + B * L;                     // 160
    float* pullp   = cntvG + B * L;                      // 1440
    unsigned int* counter = (unsigned int*)(pullp + NBLK3);
    // total ws use: ~7.6 MB

    pack_k<<<dim3(BLKX, B), 256, 0, stream>>>(tgt, tpk, partial, counter);       // 1440 blocks
    seg_sums_k<<<dim3(BLKX, C, B), 256, 0, stream>>>(tpk, emb, partial);         // 5760 blocks
    pull_k<<<dim3(BLKX, B), 256, 0, stream>>>(tpk, emb, partial, meansG, validG,
                                              cntvG, pullp, counter, (float*)d_out); // 1440 blocks
}